// Round 1
// baseline (366.618 us; speedup 1.0000x reference)
//
#include <hip/hip_runtime.h>

// ZeroUpsampling: out[b,c,2h,2w] = x[b,c,h,w], zeros elsewhere.
// x: (4,32,540,960) f32 -> out: (4,32,1080,1920) f32
// Pure memory-bound scatter; every output element written exactly once.

constexpr int W_IN  = 960;
constexpr int H_IN  = 540;
constexpr int BC    = 4 * 32;          // flattened batch*channel images
constexpr int W_OUT = 2 * W_IN;        // 1920
constexpr int QPR   = W_IN / 4;        // 240 input float4 quads per row
constexpr int OQPR  = W_OUT / 4;       // 480 output float4 quads per row
constexpr long TOTAL_Q = (long)BC * H_IN * QPR;  // 16,588,800

__global__ __launch_bounds__(256)
void zero_upsample_kernel(const float4* __restrict__ in, float4* __restrict__ out) {
    const float4 z = make_float4(0.f, 0.f, 0.f, 0.f);
    const int stride = gridDim.x * blockDim.x;
    for (int t = blockIdx.x * blockDim.x + threadIdx.x; t < (int)TOTAL_Q; t += stride) {
        // t == r * QPR + q, where r is the flat input row over (B*C*H)
        int r = t / QPR;
        int q = t - r * QPR;
        int img = r / H_IN;
        int h   = r - img * H_IN;

        float4 v = in[t];  // coalesced 16B load

        // output row (flat): img * (2*H) + 2*h ; column quad base: q*2
        int orow  = img * (2 * H_IN) + 2 * h;
        int obase = orow * OQPR + q * 2;   // fits in int32 (max ~66.36M)

        // even output row: interleave values with zeros
        out[obase]     = make_float4(v.x, 0.f, v.y, 0.f);
        out[obase + 1] = make_float4(v.z, 0.f, v.w, 0.f);
        // odd output row: all zeros
        out[obase + OQPR]     = z;
        out[obase + OQPR + 1] = z;
    }
}

extern "C" void kernel_launch(void* const* d_in, const int* in_sizes, int n_in,
                              void* d_out, int out_size, void* d_ws, size_t ws_size,
                              hipStream_t stream) {
    const float4* in  = (const float4*)d_in[0];
    float4*       out = (float4*)d_out;

    const int block = 256;
    // grid-stride: cap at 2048 blocks (256 CUs x 8 blocks/CU)
    long want = (TOTAL_Q + block - 1) / block;
    int grid = (int)(want < 2048 ? want : 2048);

    zero_upsample_kernel<<<grid, block, 0, stream>>>(in, out);
}

// Round 2
// 265.894 us; speedup vs baseline: 1.3788x; 1.3788x over previous
//
#include <hip/hip_runtime.h>

// ZeroUpsampling: out[b,c,2h,2w] = x[b,c,h,w], zeros elsewhere.
// x: (4,32,540,960) f32 -> out: (4,32,1080,1920) f32
//
// Layout trick: let t index input float2 pairs (2 horizontal pixels).
//   r  = t / 480  (flat input row over B*C*H, 480 float2 per row)
//   oq = t % 480  (output float4 quad within the row)
// Input float2 index == t exactly. Output even row base (in float4 units)
// = 2*r*480 = 960*r. Each thread:
//   - reads float2 v (coalesced, 8B/lane)
//   - writes {v.x,0,v.y,0} to even-row quad (coalesced, 16B/lane)
//   - writes zeros to the matching odd-row quad (coalesced, 16B/lane)
// Every output float4 is written exactly once.

constexpr int W_IN  = 960;
constexpr int H_IN  = 540;
constexpr int BC    = 4 * 32;
constexpr int P2PR  = W_IN / 2;                    // 480 float2 per input row
constexpr int OQPR  = (2 * W_IN) / 4;              // 480 float4 per output row
constexpr long TOTAL = (long)BC * H_IN * P2PR;     // 33,177,600 threads

__global__ __launch_bounds__(256)
void zero_upsample_kernel(const float2* __restrict__ in2, float4* __restrict__ out) {
    const float4 z = make_float4(0.f, 0.f, 0.f, 0.f);
    const int stride = gridDim.x * blockDim.x;
    for (int t = blockIdx.x * blockDim.x + threadIdx.x; t < (int)TOTAL; t += stride) {
        int r  = t / P2PR;          // flat input row
        int oq = t - r * P2PR;      // quad within row

        float2 v = in2[t];          // coalesced 8B/lane load

        int obase = 960 * r + oq;   // even output row quad index (max ~66.35M, fits int32)
        out[obase]        = make_float4(v.x, 0.f, v.y, 0.f);  // coalesced
        out[obase + OQPR] = z;                                 // odd row zeros, coalesced
    }
}

extern "C" void kernel_launch(void* const* d_in, const int* in_sizes, int n_in,
                              void* d_out, int out_size, void* d_ws, size_t ws_size,
                              hipStream_t stream) {
    const float2* in2 = (const float2*)d_in[0];
    float4*       out = (float4*)d_out;

    const int block = 256;
    long want = (TOTAL + block - 1) / block;
    int grid = (int)(want < 2048 ? want : 2048);

    zero_upsample_kernel<<<grid, block, 0, stream>>>(in2, out);
}

// Round 4
// 263.364 us; speedup vs baseline: 1.3921x; 1.0096x over previous
//
#include <hip/hip_runtime.h>

// ZeroUpsampling: out[b,c,2h,2w] = x[b,c,h,w], zeros elsewhere.
// x: (4,32,540,960) f32 -> out: (4,32,1080,1920) f32
//
// Mapping (from R1, fully coalesced):
//   t indexes input float2 pairs; r = t/480 (flat input row), oq = t%480.
//   even-row write: out4[960*r + oq]      = {v.x, 0, v.y, 0}
//   odd-row write:  out4[960*r + 480 + oq] = 0
//
// R2 change: grid chosen so the grid-stride is an exact multiple of a row
// (518,400 threads = 480 * 1080 rows). oq is loop-invariant; per-iteration
// work is pointer increments by compile-time constants; exactly 64 iters.
// R3: use native clang ext_vector types — __builtin_nontemporal_* rejects
// HIP_vector_type (struct) pointers.

typedef float vfloat2 __attribute__((ext_vector_type(2)));
typedef float vfloat4 __attribute__((ext_vector_type(4)));

constexpr int W_IN  = 960;
constexpr int H_IN  = 540;
constexpr int BC    = 4 * 32;
constexpr int P2PR  = W_IN / 2;            // 480 float2 per input row
constexpr int OQPR  = (2 * W_IN) / 4;      // 480 float4 per output row
constexpr int ROWS  = BC * H_IN;           // 69120 flat input rows

constexpr int BLOCK = 256;
constexpr int GRID  = 2025;                // 2025*256 = 518400 = 480 * 1080
constexpr int STRIDE = GRID * BLOCK;       // 518400 threads
constexpr int ROWS_PER_ITER = STRIDE / P2PR;   // 1080
constexpr int ITERS = ROWS / ROWS_PER_ITER;    // 64, exact

static_assert(STRIDE % P2PR == 0, "stride must be whole rows");
static_assert(ROWS % ROWS_PER_ITER == 0, "iteration count must be exact");

__global__ __launch_bounds__(BLOCK)
void zero_upsample_kernel(const vfloat2* __restrict__ in2, vfloat4* __restrict__ out) {
    const int t0 = blockIdx.x * BLOCK + threadIdx.x;
    const int r0 = t0 / P2PR;              // one div per thread, outside loop
    const int oq = t0 - r0 * P2PR;

    const vfloat2* ip  = in2 + t0;
    vfloat4*       ope = out + (size_t)(2 * r0) * OQPR + oq;  // even-row quad
    vfloat4*       opo = ope + OQPR;                           // odd-row quad

    constexpr size_t IN_STEP  = STRIDE;                           // float2 units
    constexpr size_t OUT_STEP = (size_t)ROWS_PER_ITER * 2 * OQPR; // float4 units

    #pragma unroll 4
    for (int i = 0; i < ITERS; ++i) {
        vfloat2 v = __builtin_nontemporal_load(ip);
        vfloat4 e = {v.x, 0.f, v.y, 0.f};
        vfloat4 z = {0.f, 0.f, 0.f, 0.f};
        __builtin_nontemporal_store(e, ope);
        __builtin_nontemporal_store(z, opo);
        ip  += IN_STEP;
        ope += OUT_STEP;
        opo += OUT_STEP;
    }
}

extern "C" void kernel_launch(void* const* d_in, const int* in_sizes, int n_in,
                              void* d_out, int out_size, void* d_ws, size_t ws_size,
                              hipStream_t stream) {
    const vfloat2* in2 = (const vfloat2*)d_in[0];
    vfloat4*       out = (vfloat4*)d_out;
    zero_upsample_kernel<<<GRID, BLOCK, 0, stream>>>(in2, out);
}

// Round 5
// 258.306 us; speedup vs baseline: 1.4193x; 1.0196x over previous
//
#include <hip/hip_runtime.h>

// ZeroUpsampling: out[b,c,2h,2w] = x[b,c,h,w], zeros elsewhere.
// x: (4,32,540,960) f32 -> out: (4,32,1080,1920) f32
//
// R4: split traffic classes into two sequential kernels to stop fine-grained
// read/write interleaving at the memory controller:
//   A) even rows: read float2, store {v.x,0,v.y,0}  (copy-class, 265R+531W MB)
//   B) odd rows:  pure zero float4 stores            (fill-class, 531W MB)
// Mapping per R2/R3: t indexes (row r = t/480, quad oq = t%480); grid-stride
// is an exact multiple of rows (518,400 = 480*1080) so oq is loop-invariant
// and the loop is pure pointer increments, exactly 64 iterations.

typedef float vfloat2 __attribute__((ext_vector_type(2)));
typedef float vfloat4 __attribute__((ext_vector_type(4)));

constexpr int W_IN  = 960;
constexpr int H_IN  = 540;
constexpr int BC    = 4 * 32;
constexpr int P2PR  = W_IN / 2;            // 480 float2 per input row
constexpr int OQPR  = (2 * W_IN) / 4;      // 480 float4 per output row
constexpr int ROWS  = BC * H_IN;           // 69120 flat input rows

constexpr int BLOCK = 256;
constexpr int GRID  = 2025;                // 2025*256 = 518400 = 480 * 1080
constexpr int STRIDE = GRID * BLOCK;
constexpr int ROWS_PER_ITER = STRIDE / P2PR;   // 1080
constexpr int ITERS = ROWS / ROWS_PER_ITER;    // 64, exact
constexpr size_t OUT_STEP = (size_t)ROWS_PER_ITER * 2 * OQPR; // float4 units

static_assert(STRIDE % P2PR == 0, "stride must be whole rows");
static_assert(ROWS % ROWS_PER_ITER == 0, "iteration count must be exact");

// Kernel A: even output rows (the data-carrying half). Copy-class traffic.
__global__ __launch_bounds__(BLOCK)
void upsample_even_kernel(const vfloat2* __restrict__ in2, vfloat4* __restrict__ out) {
    const int t0 = blockIdx.x * BLOCK + threadIdx.x;
    const int r0 = t0 / P2PR;
    const int oq = t0 - r0 * P2PR;

    const vfloat2* ip  = in2 + t0;
    vfloat4*       ope = out + (size_t)(2 * r0) * OQPR + oq;

    #pragma unroll 4
    for (int i = 0; i < ITERS; ++i) {
        vfloat2 v = __builtin_nontemporal_load(ip);
        vfloat4 e = {v.x, 0.f, v.y, 0.f};
        __builtin_nontemporal_store(e, ope);
        ip  += STRIDE;
        ope += OUT_STEP;
    }
}

// Kernel B: odd output rows, pure zero fill. Fill-class traffic (no reads).
__global__ __launch_bounds__(BLOCK)
void upsample_zero_kernel(vfloat4* __restrict__ out) {
    const int t0 = blockIdx.x * BLOCK + threadIdx.x;
    const int r0 = t0 / P2PR;
    const int oq = t0 - r0 * P2PR;

    vfloat4* opo = out + (size_t)(2 * r0 + 1) * OQPR + oq;
    const vfloat4 z = {0.f, 0.f, 0.f, 0.f};

    #pragma unroll 4
    for (int i = 0; i < ITERS; ++i) {
        __builtin_nontemporal_store(z, opo);
        opo += OUT_STEP;
    }
}

extern "C" void kernel_launch(void* const* d_in, const int* in_sizes, int n_in,
                              void* d_out, int out_size, void* d_ws, size_t ws_size,
                              hipStream_t stream) {
    const vfloat2* in2 = (const vfloat2*)d_in[0];
    vfloat4*       out = (vfloat4*)d_out;
    upsample_even_kernel<<<GRID, BLOCK, 0, stream>>>(in2, out);
    upsample_zero_kernel<<<GRID, BLOCK, 0, stream>>>(out);
}